// Round 18
// baseline (81.853 us; speedup 1.0000x reference)
//
#include <hip/hip_runtime.h>
#include <math.h>

#define Bsz 4096
#define Dk 128
#define RPB 16                   // rows per block (full-row blocks)
#define NBLK (Bsz / RPB)         // 256 blocks
#define THREADS 1024             // 16 waves
#define NW 16
#define CPW (Bsz / NW)           // 256 cols per wave
#define CT (CPW / 16)            // 16 col-tiles per wave
#define PFD 4                    // prefetch depth (tiles in flight)

typedef __attribute__((ext_vector_type(8))) short short8;
typedef __attribute__((ext_vector_type(4))) float f32x4;

__device__ __forceinline__ unsigned short f2bf(float f) {
  unsigned u = __float_as_uint(f);
  u = (u + 0x7fffu + ((u >> 16) & 1u)) >> 16;   // RNE
  return (unsigned short)u;
}

// Xt layout: [kb][col][8] with kb = k/8 (16 x 4096 x 8 bf16):
// fragment loads are 4 x 256B contiguous segments per wave.
__global__ __launch_bounds__(256)
void convert_kernel(const float* __restrict__ X, short* __restrict__ Xt) {
  int i = blockIdx.x * 256 + threadIdx.x;     // 65536 = 4096 cols x 16 kb
  int col = i >> 4, kb = i & 15;
  const float4* q = (const float4*)(X + col * Dk + kb * 8);
  float4 v0 = q[0], v1 = q[1];
  short8 r;
  r[0] = (short)f2bf(v0.x); r[1] = (short)f2bf(v0.y);
  r[2] = (short)f2bf(v0.z); r[3] = (short)f2bf(v0.w);
  r[4] = (short)f2bf(v1.x); r[5] = (short)f2bf(v1.y);
  r[6] = (short)f2bf(v1.z); r[7] = (short)f2bf(v1.w);
  *(short8*)(Xt + (size_t)(kb * Bsz + col) * 8) = r;
}

__device__ __forceinline__ short8 ldfrag(const short* __restrict__ Xt, int col, int ks, int lg) {
  return *(const short8*)(Xt + (size_t)(((ks << 2) + lg) * Bsz + col) * 8);
}

// Monolithic double sweep (r14 structure) + 4-deep software prefetch of the
// B fragments in BOTH GEMM loops. Block owns 16 FULL rows; wave owns a
// 256-col strip; thresholds exact via 2KB LDS reduce between phases.
__global__ __launch_bounds__(THREADS, 4)
void mono(const short* __restrict__ Xt, const int* __restrict__ labels,
          float* __restrict__ row_loss, float* __restrict__ row_valid) {
  const int tid = threadIdx.x;
  const int w  = tid >> 6;
  const int l  = tid & 63;
  const int lg = l >> 4;     // k-group / C row-group
  const int lr = l & 15;     // A row-in-tile / B,C col-in-tile
  const int r0 = blockIdx.x * RPB;

  __shared__ float red[2][NW][RPB];
  __shared__ float thp_s[RPB], thn_s[RPB], vld_s[RPB];

  // A fragments: block's 16 rows x K=128 (16 VGPR), shared by all waves.
  short8 afrag[4];
  for (int ks = 0; ks < 4; ++ks) afrag[ks] = ldfrag(Xt, r0 + lr, ks, lg);
  int labr[4];
  for (int rg = 0; rg < 4; ++rg) labr[rg] = labels[r0 + lg * 4 + rg];

  // ---- phase A: min(pos excl self)/max(neg), 4-deep prefetched ----
  float mnp[4], mxn[4];
  for (int rg = 0; rg < 4; ++rg) { mnp[rg] = INFINITY; mxn[rg] = -INFINITY; }

  short8 pf[PFD][4];
  int    plab[PFD];
#pragma unroll
  for (int t = 0; t < PFD; ++t) {
    const int colv = w * CPW + t * 16 + lr;
    for (int ks = 0; ks < 4; ++ks) pf[t][ks] = ldfrag(Xt, colv, ks, lg);
    plab[t] = labels[colv];
  }

#pragma unroll
  for (int ct = 0; ct < CT; ++ct) {
    const int ctc  = w * CPW + ct * 16;
    short8 bfrag[4];
    for (int ks = 0; ks < 4; ++ks) bfrag[ks] = pf[ct & (PFD - 1)][ks];
    const int labc = plab[ct & (PFD - 1)];
    if (ct + PFD < CT) {                      // refill just-consumed slot
      const int cnx = w * CPW + (ct + PFD) * 16 + lr;
      for (int ks = 0; ks < 4; ++ks) pf[ct & (PFD - 1)][ks] = ldfrag(Xt, cnx, ks, lg);
      plab[ct & (PFD - 1)] = labels[cnx];
    }

    f32x4 acc = {0.f, 0.f, 0.f, 0.f};
    for (int ks = 0; ks < 4; ++ks)
      acc = __builtin_amdgcn_mfma_f32_16x16x32_bf16(afrag[ks], bfrag[ks], acc, 0, 0, 0);
    const bool diag = (ctc == r0);   // wave-uniform
    // C/D layout (verified): col = lane&15, row = (lane>>4)*4 + reg
#pragma unroll
    for (int rg = 0; rg < 4; ++rg) {
      float s    = acc[rg];
      bool  eq   = (labc == labr[rg]);
      bool  self = diag && (lr == lg * 4 + rg);
      if (eq && !self) mnp[rg] = fminf(mnp[rg], s);
      if (!eq)         mxn[rg] = fmaxf(mxn[rg], s);
    }
  }
  for (int rg = 0; rg < 4; ++rg) {
    for (int m = 1; m < 16; m <<= 1) {
      mnp[rg] = fminf(mnp[rg], __shfl_xor(mnp[rg], m, 64));
      mxn[rg] = fmaxf(mxn[rg], __shfl_xor(mxn[rg], m, 64));
    }
  }
  if (lr == 0)
    for (int rg = 0; rg < 4; ++rg) {
      red[0][w][lg * 4 + rg] = mnp[rg];
      red[1][w][lg * 4 + rg] = mxn[rg];
    }
  __syncthreads();

  if (tid < RPB) {
    float a = INFINITY, b = -INFINITY;
    for (int ww = 0; ww < NW; ++ww) {
      a = fminf(a, red[0][ww][tid]);
      b = fmaxf(b, red[1][ww][tid]);
    }
    thp_s[tid] = b + 0.1f;                    // pos_keep: s < max_neg + 0.1
    thn_s[tid] = a - 0.1f;                    // neg_keep: s > min_pos - 0.1
    vld_s[tid] = (a - 0.1f < b) ? 1.f : 0.f;  // any pos kept && any neg kept
  }
  __syncthreads();

  // ---- phase B: exact-threshold exp sums, same prefetch ----
  float tp[4], tn[4];
  for (int rg = 0; rg < 4; ++rg) {
    tp[rg] = thp_s[lg * 4 + rg];
    tn[rg] = thn_s[lg * 4 + rg];
  }
  float ap[4] = {0.f, 0.f, 0.f, 0.f}, an[4] = {0.f, 0.f, 0.f, 0.f};

#pragma unroll
  for (int t = 0; t < PFD; ++t) {
    const int colv = w * CPW + t * 16 + lr;
    for (int ks = 0; ks < 4; ++ks) pf[t][ks] = ldfrag(Xt, colv, ks, lg);
    plab[t] = labels[colv];
  }

#pragma unroll
  for (int ct = 0; ct < CT; ++ct) {
    const int ctc  = w * CPW + ct * 16;
    short8 bfrag[4];
    for (int ks = 0; ks < 4; ++ks) bfrag[ks] = pf[ct & (PFD - 1)][ks];
    const int labc = plab[ct & (PFD - 1)];
    if (ct + PFD < CT) {
      const int cnx = w * CPW + (ct + PFD) * 16 + lr;
      for (int ks = 0; ks < 4; ++ks) pf[ct & (PFD - 1)][ks] = ldfrag(Xt, cnx, ks, lg);
      plab[ct & (PFD - 1)] = labels[cnx];
    }

    f32x4 acc = {0.f, 0.f, 0.f, 0.f};
    for (int ks = 0; ks < 4; ++ks)
      acc = __builtin_amdgcn_mfma_f32_16x16x32_bf16(afrag[ks], bfrag[ks], acc, 0, 0, 0);
    const bool diag = (ctc == r0);
#pragma unroll
    for (int rg = 0; rg < 4; ++rg) {
      float s    = acc[rg];
      bool  eq   = (labc == labr[rg]);
      bool  self = diag && (lr == lg * 4 + rg);
      bool  kp   = eq && !self && (s < tp[rg]);
      bool  kn   = (!eq) && (s > tn[rg]);
      float argp = fmaf(s, -2.885390082f, 1.442695041f);   // -2*(s-0.5)*log2e
      float argn = fmaf(s, 57.70780163f, -28.85390082f);   // 40*(s-0.5)*log2e
      float e = exp2f(kp ? argp : argn);
      ap[rg] += kp ? e : 0.f;
      an[rg] += kn ? e : 0.f;
    }
  }
  for (int rg = 0; rg < 4; ++rg) {
    for (int m = 1; m < 16; m <<= 1) {
      ap[rg] += __shfl_xor(ap[rg], m, 64);
      an[rg] += __shfl_xor(an[rg], m, 64);
    }
  }
  __syncthreads();   // red[] free for reuse
  if (lr == 0)
    for (int rg = 0; rg < 4; ++rg) {
      red[0][w][lg * 4 + rg] = ap[rg];
      red[1][w][lg * 4 + rg] = an[rg];
    }
  __syncthreads();

  if (tid < RPB) {
    float P = 0.f, N = 0.f;
    for (int ww = 0; ww < NW; ++ww) { P += red[0][ww][tid]; N += red[1][ww][tid]; }
    bool v = vld_s[tid] > 0.f;
    row_loss[r0 + tid]  = v ? (log1pf(P) * 0.5f + log1pf(N) * 0.025f) : 0.f;
    row_valid[r0 + tid] = v ? 1.f : 0.f;
  }
}

__global__ __launch_bounds__(1024)
void finalize(const float* __restrict__ row_loss, const float* __restrict__ row_valid,
              float* __restrict__ out) {
  int tid = threadIdx.x;
  float s = 0.f, c = 0.f;
  for (int r = tid; r < Bsz; r += 1024) {
    s += row_loss[r];
    c += row_valid[r];
  }
  for (int m = 1; m < 64; m <<= 1) {
    s += __shfl_xor(s, m, 64);
    c += __shfl_xor(c, m, 64);
  }
  __shared__ float rs[16], rc[16];
  int w = tid >> 6, lz = tid & 63;
  if (lz == 0) { rs[w] = s; rc[w] = c; }
  __syncthreads();
  if (tid == 0) {
    float ts = 0.f, tc = 0.f;
    for (int i = 0; i < 16; ++i) { ts += rs[i]; tc += rc[i]; }
    out[0] = ts / fmaxf(tc, 1.0f);
  }
}

extern "C" void kernel_launch(void* const* d_in, const int* in_sizes, int n_in,
                              void* d_out, int out_size, void* d_ws, size_t ws_size,
                              hipStream_t stream) {
  const float* X      = (const float*)d_in[0];
  const int*   labels = (const int*)d_in[1];

  char* ws = (char*)d_ws;
  short* Xt        = (short*)ws;                      // 1 MB (k-block transposed bf16)
  float* row_loss  = (float*)(ws + 1048576);          // 16 KB
  float* row_valid = (float*)(ws + 1048576 + 16384);  // 16 KB

  convert_kernel<<<256, 256, 0, stream>>>(X, Xt);
  mono<<<NBLK, THREADS, 0, stream>>>(Xt, labels, row_loss, row_valid);
  finalize<<<1, 1024, 0, stream>>>(row_loss, row_valid, (float*)d_out);
}

// Round 19
// 38.498 us; speedup vs baseline: 2.1261x; 2.1261x over previous
//
#include <hip/hip_runtime.h>
#include <math.h>

#define Bsz 4096
#define Dk 128
#define RPB 16                   // rows per block (full-row blocks)
#define NBLK (Bsz / RPB)         // 256 blocks
#define THREADS 1024             // 16 waves
#define NW 16
#define CPW (Bsz / NW)           // 256 cols per wave
#define CT (CPW / 16)            // 16 col-tiles per wave

typedef __attribute__((ext_vector_type(8))) short short8;
typedef __attribute__((ext_vector_type(4))) float f32x4;

__device__ __forceinline__ unsigned short f2bf(float f) {
  unsigned u = __float_as_uint(f);
  u = (u + 0x7fffu + ((u >> 16) & 1u)) >> 16;   // RNE
  return (unsigned short)u;
}

// Xt layout: [kb][col][8] with kb = k/8 (16 x 4096 x 8 bf16):
// fragment loads are 4 x 256B contiguous segments per wave.
__global__ __launch_bounds__(256)
void convert_kernel(const float* __restrict__ X, short* __restrict__ Xt) {
  int i = blockIdx.x * 256 + threadIdx.x;     // 65536 = 4096 cols x 16 kb
  int col = i >> 4, kb = i & 15;
  const float4* q = (const float4*)(X + col * Dk + kb * 8);
  float4 v0 = q[0], v1 = q[1];
  short8 r;
  r[0] = (short)f2bf(v0.x); r[1] = (short)f2bf(v0.y);
  r[2] = (short)f2bf(v0.z); r[3] = (short)f2bf(v0.w);
  r[4] = (short)f2bf(v1.x); r[5] = (short)f2bf(v1.y);
  r[6] = (short)f2bf(v1.z); r[7] = (short)f2bf(v1.w);
  *(short8*)(Xt + (size_t)(kb * Bsz + col) * 8) = r;
}

__device__ __forceinline__ short8 ldfrag(const short* __restrict__ Xt, int col, int ks, int lg) {
  return *(const short8*)(Xt + (size_t)(((ks << 2) + lg) * Bsz + col) * 8);
}

// Monolithic double sweep: block owns 16 FULL rows. Phase A: GEMM over all
// 4096 cols (16 waves x 256-col strips) -> exact row min(pos)/max(neg) via
// 2KB LDS reduce. Phase B: re-GEMM with exact thresholds (warm-L2 re-read)
// -> exp sums -> per-row loss + validity. No cross-block communication.
__global__ __launch_bounds__(THREADS, 4)
void mono(const short* __restrict__ Xt, const int* __restrict__ labels,
          float* __restrict__ row_loss, float* __restrict__ row_valid) {
  const int tid = threadIdx.x;
  const int w  = tid >> 6;
  const int l  = tid & 63;
  const int lg = l >> 4;     // k-group / C row-group
  const int lr = l & 15;     // A row-in-tile / B,C col-in-tile
  const int r0 = blockIdx.x * RPB;

  __shared__ float red[2][NW][RPB];
  __shared__ float thp_s[RPB], thn_s[RPB], vld_s[RPB];

  // A fragments: block's 16 rows x K=128 (16 VGPR), shared by all waves.
  short8 afrag[4];
  for (int ks = 0; ks < 4; ++ks) afrag[ks] = ldfrag(Xt, r0 + lr, ks, lg);
  int labr[4];
  for (int rg = 0; rg < 4; ++rg) labr[rg] = labels[r0 + lg * 4 + rg];

  // ---- phase A: min(pos excl self) / max(neg) over this wave's strip ----
  float mnp[4], mxn[4];
  for (int rg = 0; rg < 4; ++rg) { mnp[rg] = INFINITY; mxn[rg] = -INFINITY; }

  for (int ct = 0; ct < CT; ++ct) {
    const int ctc  = w * CPW + ct * 16;
    const int colv = ctc + lr;
    short8 bfrag[4];
    for (int ks = 0; ks < 4; ++ks) bfrag[ks] = ldfrag(Xt, colv, ks, lg);
    const int labc = labels[colv];

    f32x4 acc = {0.f, 0.f, 0.f, 0.f};
    for (int ks = 0; ks < 4; ++ks)
      acc = __builtin_amdgcn_mfma_f32_16x16x32_bf16(afrag[ks], bfrag[ks], acc, 0, 0, 0);
    const bool diag = (ctc == r0);   // wave-uniform
    // C/D layout (verified): col = lane&15, row = (lane>>4)*4 + reg
    for (int rg = 0; rg < 4; ++rg) {
      float s    = acc[rg];
      bool  eq   = (labc == labr[rg]);
      bool  self = diag && (lr == lg * 4 + rg);
      if (eq && !self) mnp[rg] = fminf(mnp[rg], s);
      if (!eq)         mxn[rg] = fmaxf(mxn[rg], s);
    }
  }
  for (int rg = 0; rg < 4; ++rg) {
    for (int m = 1; m < 16; m <<= 1) {
      mnp[rg] = fminf(mnp[rg], __shfl_xor(mnp[rg], m, 64));
      mxn[rg] = fmaxf(mxn[rg], __shfl_xor(mxn[rg], m, 64));
    }
  }
  if (lr == 0)
    for (int rg = 0; rg < 4; ++rg) {
      red[0][w][lg * 4 + rg] = mnp[rg];
      red[1][w][lg * 4 + rg] = mxn[rg];
    }
  __syncthreads();

  if (tid < RPB) {
    float a = INFINITY, b = -INFINITY;
    for (int ww = 0; ww < NW; ++ww) {
      a = fminf(a, red[0][ww][tid]);
      b = fmaxf(b, red[1][ww][tid]);
    }
    thp_s[tid] = b + 0.1f;                    // pos_keep: s < max_neg + 0.1
    thn_s[tid] = a - 0.1f;                    // neg_keep: s > min_pos - 0.1
    vld_s[tid] = (a - 0.1f < b) ? 1.f : 0.f;  // any pos kept && any neg kept
  }
  __syncthreads();

  // ---- phase B: exact-threshold exp sums over the same strip ----
  float tp[4], tn[4];
  for (int rg = 0; rg < 4; ++rg) {
    tp[rg] = thp_s[lg * 4 + rg];
    tn[rg] = thn_s[lg * 4 + rg];
  }
  float ap[4] = {0.f, 0.f, 0.f, 0.f}, an[4] = {0.f, 0.f, 0.f, 0.f};

  for (int ct = 0; ct < CT; ++ct) {
    const int ctc  = w * CPW + ct * 16;
    const int colv = ctc + lr;
    short8 bfrag[4];
    for (int ks = 0; ks < 4; ++ks) bfrag[ks] = ldfrag(Xt, colv, ks, lg);
    const int labc = labels[colv];

    f32x4 acc = {0.f, 0.f, 0.f, 0.f};
    for (int ks = 0; ks < 4; ++ks)
      acc = __builtin_amdgcn_mfma_f32_16x16x32_bf16(afrag[ks], bfrag[ks], acc, 0, 0, 0);
    const bool diag = (ctc == r0);
    for (int rg = 0; rg < 4; ++rg) {
      float s    = acc[rg];
      bool  eq   = (labc == labr[rg]);
      bool  self = diag && (lr == lg * 4 + rg);
      bool  kp   = eq && !self && (s < tp[rg]);
      bool  kn   = (!eq) && (s > tn[rg]);
      float argp = fmaf(s, -2.885390082f, 1.442695041f);   // -2*(s-0.5)*log2e
      float argn = fmaf(s, 57.70780163f, -28.85390082f);   // 40*(s-0.5)*log2e
      float e = exp2f(kp ? argp : argn);
      ap[rg] += kp ? e : 0.f;
      an[rg] += kn ? e : 0.f;
    }
  }
  for (int rg = 0; rg < 4; ++rg) {
    for (int m = 1; m < 16; m <<= 1) {
      ap[rg] += __shfl_xor(ap[rg], m, 64);
      an[rg] += __shfl_xor(an[rg], m, 64);
    }
  }
  __syncthreads();   // red[] free for reuse
  if (lr == 0)
    for (int rg = 0; rg < 4; ++rg) {
      red[0][w][lg * 4 + rg] = ap[rg];
      red[1][w][lg * 4 + rg] = an[rg];
    }
  __syncthreads();

  if (tid < RPB) {
    float P = 0.f, N = 0.f;
    for (int ww = 0; ww < NW; ++ww) { P += red[0][ww][tid]; N += red[1][ww][tid]; }
    bool v = vld_s[tid] > 0.f;
    row_loss[r0 + tid]  = v ? (log1pf(P) * 0.5f + log1pf(N) * 0.025f) : 0.f;
    row_valid[r0 + tid] = v ? 1.f : 0.f;
  }
}

__global__ __launch_bounds__(1024)
void finalize(const float* __restrict__ row_loss, const float* __restrict__ row_valid,
              float* __restrict__ out) {
  int tid = threadIdx.x;
  float s = 0.f, c = 0.f;
  for (int r = tid; r < Bsz; r += 1024) {
    s += row_loss[r];
    c += row_valid[r];
  }
  for (int m = 1; m < 64; m <<= 1) {
    s += __shfl_xor(s, m, 64);
    c += __shfl_xor(c, m, 64);
  }
  __shared__ float rs[16], rc[16];
  int w = tid >> 6, lz = tid & 63;
  if (lz == 0) { rs[w] = s; rc[w] = c; }
  __syncthreads();
  if (tid == 0) {
    float ts = 0.f, tc = 0.f;
    for (int i = 0; i < 16; ++i) { ts += rs[i]; tc += rc[i]; }
    out[0] = ts / fmaxf(tc, 1.0f);
  }
}

extern "C" void kernel_launch(void* const* d_in, const int* in_sizes, int n_in,
                              void* d_out, int out_size, void* d_ws, size_t ws_size,
                              hipStream_t stream) {
  const float* X      = (const float*)d_in[0];
  const int*   labels = (const int*)d_in[1];

  char* ws = (char*)d_ws;
  short* Xt        = (short*)ws;                      // 1 MB (k-block transposed bf16)
  float* row_loss  = (float*)(ws + 1048576);          // 16 KB
  float* row_valid = (float*)(ws + 1048576 + 16384);  // 16 KB

  convert_kernel<<<256, 256, 0, stream>>>(X, Xt);
  mono<<<NBLK, THREADS, 0, stream>>>(Xt, labels, row_loss, row_valid);
  finalize<<<1, 1024, 0, stream>>>(row_loss, row_valid, (float*)d_out);
}